// Round 1
// baseline (11617.052 us; speedup 1.0000x reference)
//
#include <hip/hip_runtime.h>
#include <hip/hip_bf16.h>

#define NN 50000
#define NEDG 800000
#define CH 32
#define NCH (NN*CH)
#define NBF 8

constexpr float RCUT_F = 5.0f;
constexpr float SQRT3_F = 1.7320508075688772f;
constexpr float INV_SQRT3_F = 0.57735026918962576f;
constexpr float INV_SQRT2_F = 0.70710678118654752f;
constexpr float PI_F = 3.14159265358979323846f;

__device__ __forceinline__ float silu_f(float x) { return x / (1.0f + __expf(-x)); }

// -------------------- edge preprocessing + compaction --------------------
__global__ void k_edge_prep(const float* __restrict__ pos, const int* __restrict__ ei,
                            int* __restrict__ cnt, int* __restrict__ esend,
                            int* __restrict__ erecv, float* __restrict__ egeo)
{
    int e = blockIdx.x * 256 + threadIdx.x;
    if (e >= NEDG) return;
    int s = ei[e], r = ei[NEDG + e];
    float dx = pos[r*3+0] - pos[s*3+0];
    float dy = pos[r*3+1] - pos[s*3+1];
    float dz = pos[r*3+2] - pos[s*3+2];
    float len = sqrtf(dx*dx + dy*dy + dz*dz);
    // edges with len==0 or len>=RCUT produce exactly-zero messages in the reference
    if (!(len > 0.0f && len < RCUT_F)) return;
    int idx = atomicAdd(cnt, 1);
    esend[idx] = s; erecv[idx] = r;
    float inv = 1.0f / (len + 1e-9f);
    float x = len * (1.0f / RCUT_F);
    float x2 = x*x, x3 = x2*x;
    float x6 = x3*x3;
    float cut = 1.0f - 28.0f*x6 + 48.0f*x6*x - 21.0f*x6*x2;   // p=6 poly cutoff
    float pref = 0.632455532033675866f * inv * cut;            // sqrt(2/RCUT)
    float* gg = egeo + (size_t)idx * 12;
    gg[0] = SQRT3_F * dx * inv;
    gg[1] = SQRT3_F * dy * inv;
    gg[2] = SQRT3_F * dz * inv;
    float arg = PI_F * len * (1.0f / RCUT_F);
    #pragma unroll
    for (int k = 0; k < NBF; ++k) gg[3+k] = pref * sinf((float)(k+1) * arg);
    gg[11] = 0.f;
}

// -------------------- node embedding init --------------------
__global__ void k_embed(const int* __restrict__ species, const float* __restrict__ wemb,
                        float* __restrict__ f)
{
    int t = blockIdx.x * 256 + threadIdx.x;
    if (t >= NCH) return;
    int n = t >> 5, c = t & 31;
    f[t] = wemb[species[n]*CH + c];
    f[NCH + t] = 0.f;
    f[2*NCH + t] = 0.f;
    f[3*NCH + t] = 0.f;
}

// -------------------- per-l channel-mixing linear (linear_up) --------------------
__global__ void k_node_linear(const float* __restrict__ fin, const float* __restrict__ W,
                              float* __restrict__ fout)
{
    int t = blockIdx.x * 256 + threadIdx.x;   // ((n*4)+comp)*32 + d
    int d = t & 31;
    int comp = (t >> 5) & 3;
    int n = t >> 7;
    if (n >= NN) return;
    const float* Wc = W + (comp ? 1024 : 0);
    const float* row = fin + comp*NCH + n*CH;
    float acc = 0.f;
    #pragma unroll
    for (int c = 0; c < 32; ++c) acc += row[c] * Wc[c*32 + d];
    fout[comp*NCH + n*CH + d] = acc;
}

// -------------------- fused edge kernel: MLP + gather + CG product + scatter ---------
// 32 lanes per edge-group (lane = channel), 4 edges per group, 8 groups per block.
__global__ void k_edge(const float* __restrict__ fu, float* __restrict__ M,
                       const float* __restrict__ w1g, const float* __restrict__ w2g,
                       const float* __restrict__ w3g,
                       const int* __restrict__ esend, const int* __restrict__ erecv,
                       const float* __restrict__ egeo, const int* __restrict__ cntp)
{
    __shared__ float4 s_w2[1024];   // [k<32][l<32] = (w2[k][l], w2[k][l+32], w2[k+32][l], w2[k+32][l+32])
    __shared__ float  s_w3[10240];  // [j][160]
    __shared__ float4 s_h[256];     // [group][32] h-broadcast staging (half of h at a time)

    const int tid = threadIdx.x;
    for (int t = tid; t < 1024; t += 256) {
        int k = t >> 5, l = t & 31;
        s_w2[t] = make_float4(w2g[k*64 + l],       w2g[k*64 + 32 + l],
                              w2g[(k+32)*64 + l],  w2g[(k+32)*64 + 32 + l]);
    }
    for (int t = tid; t < 10240; t += 256) s_w3[t] = w3g[t];
    __syncthreads();

    const int lane = tid & 31;
    const int g = tid >> 5;
    float4* s_hg = s_h + g*32;

    // w1 columns held in registers (lane j and j+32)
    float w1a[8], w1b[8];
    #pragma unroll
    for (int k = 0; k < 8; ++k) { w1a[k] = w1g[k*64 + lane]; w1b[k] = w1g[k*64 + 32 + lane]; }

    const int nact = *cntp;
    const int nchunk = (nact + 31) >> 5;

    for (int chunk = blockIdx.x; chunk < nchunk; chunk += gridDim.x) {
        const int e0 = chunk*32 + g*4;
        const int nv = nact - e0;   // #valid edges for this group (may be <=0)
        int se[4], re[4];
        float y1x[4], y1y[4], y1z[4];
        float h1a[4], h1b[4];
        #pragma unroll
        for (int e = 0; e < 4; ++e) {
            int eic = (e < nv) ? (e0 + e) : 0;
            se[e] = esend[eic]; re[e] = erecv[eic];
            const float* gg = egeo + (size_t)eic * 12;
            y1x[e] = gg[0]; y1y[e] = gg[1]; y1z[e] = gg[2];
            float aa = 0.f, ab = 0.f;
            #pragma unroll
            for (int k = 0; k < 8; ++k) { float efk = gg[3+k]; aa += efk*w1a[k]; ab += efk*w1b[k]; }
            h1a[e] = silu_f(aa); h1b[e] = silu_f(ab);
        }

        // ---- h2 = silu(h1 @ w2) ----
        float h2a[4] = {0,0,0,0}, h2b[4] = {0,0,0,0};
        s_hg[lane] = make_float4(h1a[0], h1a[1], h1a[2], h1a[3]);
        #pragma unroll
        for (int k = 0; k < 32; ++k) {
            float4 hh = s_hg[k];
            float4 wq = s_w2[k*32 + lane];
            h2a[0] += hh.x*wq.x; h2b[0] += hh.x*wq.y;
            h2a[1] += hh.y*wq.x; h2b[1] += hh.y*wq.y;
            h2a[2] += hh.z*wq.x; h2b[2] += hh.z*wq.y;
            h2a[3] += hh.w*wq.x; h2b[3] += hh.w*wq.y;
        }
        s_hg[lane] = make_float4(h1b[0], h1b[1], h1b[2], h1b[3]);
        #pragma unroll
        for (int k = 0; k < 32; ++k) {
            float4 hh = s_hg[k];
            float4 wq = s_w2[k*32 + lane];
            h2a[0] += hh.x*wq.z; h2b[0] += hh.x*wq.w;
            h2a[1] += hh.y*wq.z; h2b[1] += hh.y*wq.w;
            h2a[2] += hh.z*wq.z; h2b[2] += hh.z*wq.w;
            h2a[3] += hh.w*wq.z; h2b[3] += hh.w*wq.w;
        }
        #pragma unroll
        for (int e = 0; e < 4; ++e) { h2a[e] = silu_f(h2a[e]); h2b[e] = silu_f(h2b[e]); }

        // ---- wgt = h2 @ w3 : 5 CG-path weights per channel ----
        float wg0[4]={0,0,0,0}, wg1[4]={0,0,0,0}, wg2[4]={0,0,0,0},
              wg3[4]={0,0,0,0}, wg4[4]={0,0,0,0};
        s_hg[lane] = make_float4(h2a[0], h2a[1], h2a[2], h2a[3]);
        #pragma unroll
        for (int j = 0; j < 32; ++j) {
            float4 hh = s_hg[j];
            const float* w3r = s_w3 + j*160 + lane;
            float v0 = w3r[0], v1 = w3r[32], v2 = w3r[64], v3 = w3r[96], v4 = w3r[128];
            wg0[0]+=hh.x*v0; wg0[1]+=hh.y*v0; wg0[2]+=hh.z*v0; wg0[3]+=hh.w*v0;
            wg1[0]+=hh.x*v1; wg1[1]+=hh.y*v1; wg1[2]+=hh.z*v1; wg1[3]+=hh.w*v1;
            wg2[0]+=hh.x*v2; wg2[1]+=hh.y*v2; wg2[2]+=hh.z*v2; wg2[3]+=hh.w*v2;
            wg3[0]+=hh.x*v3; wg3[1]+=hh.y*v3; wg3[2]+=hh.z*v3; wg3[3]+=hh.w*v3;
            wg4[0]+=hh.x*v4; wg4[1]+=hh.y*v4; wg4[2]+=hh.z*v4; wg4[3]+=hh.w*v4;
        }
        s_hg[lane] = make_float4(h2b[0], h2b[1], h2b[2], h2b[3]);
        #pragma unroll
        for (int j = 0; j < 32; ++j) {
            float4 hh = s_hg[j];
            const float* w3r = s_w3 + (j+32)*160 + lane;
            float v0 = w3r[0], v1 = w3r[32], v2 = w3r[64], v3 = w3r[96], v4 = w3r[128];
            wg0[0]+=hh.x*v0; wg0[1]+=hh.y*v0; wg0[2]+=hh.z*v0; wg0[3]+=hh.w*v0;
            wg1[0]+=hh.x*v1; wg1[1]+=hh.y*v1; wg1[2]+=hh.z*v1; wg1[3]+=hh.w*v1;
            wg2[0]+=hh.x*v2; wg2[1]+=hh.y*v2; wg2[2]+=hh.z*v2; wg2[3]+=hh.w*v2;
            wg3[0]+=hh.x*v3; wg3[1]+=hh.y*v3; wg3[2]+=hh.z*v3; wg3[3]+=hh.w*v3;
            wg4[0]+=hh.x*v4; wg4[1]+=hh.y*v4; wg4[2]+=hh.z*v4; wg4[3]+=hh.w*v4;
        }

        // ---- gather sender features, CG tensor product, scatter to receivers ----
        #pragma unroll
        for (int e = 0; e < 4; ++e) {
            if (e < nv) {
                const float* fr = fu + (size_t)se[e]*CH + lane;
                float x0 = fr[0];
                float xx = fr[NCH], xy = fr[2*NCH], xz = fr[3*NCH];
                float dot = xx*y1x[e] + xy*y1y[e] + xz*y1z[e];
                float m0 = wg0[e]*x0 + wg3[e]*dot*INV_SQRT3_F;
                float cx = xy*y1z[e] - xz*y1y[e];
                float cy = xz*y1x[e] - xx*y1z[e];
                float cz = xx*y1y[e] - xy*y1x[e];
                float a = wg1[e]*x0;
                float m1x = a*y1x[e] + wg2[e]*xx + wg4[e]*cx*INV_SQRT2_F;
                float m1y = a*y1y[e] + wg2[e]*xy + wg4[e]*cy*INV_SQRT2_F;
                float m1z = a*y1z[e] + wg2[e]*xz + wg4[e]*cz*INV_SQRT2_F;
                float* mr = M + (size_t)re[e]*CH + lane;
                atomicAdd(mr,            m0);
                atomicAdd(mr + NCH,      m1x);
                atomicAdd(mr + 2*NCH,    m1y);
                atomicAdd(mr + 3*NCH,    m1z);
            }
        }
    }
}

// ------- fused: interaction linear + element product basis + product linear -------
__global__ void k_node_out(const float* __restrict__ M, const int* __restrict__ species,
                           const float* __restrict__ wlin, const float* __restrict__ wprod,
                           const float* __restrict__ wout, float* __restrict__ f,
                           float* __restrict__ dout)
{
    __shared__ float s_wl[2048];
    __shared__ float s_wo[2048];
    __shared__ float s_v[8][4][32];
    int tid = threadIdx.x;
    for (int t = tid; t < 2048; t += 256) { s_wl[t] = wlin[t]; s_wo[t] = wout[t]; }
    __syncthreads();
    int lane = tid & 31, g = tid >> 5;
    int n = blockIdx.x * 8 + g;   // NN divisible by 8

    float m0  = M[(size_t)n*CH + lane];
    float m1x = M[NCH + (size_t)n*CH + lane];
    float m1y = M[2*NCH + (size_t)n*CH + lane];
    float m1z = M[3*NCH + (size_t)n*CH + lane];
    s_v[g][0][lane] = m0; s_v[g][1][lane] = m1x; s_v[g][2][lane] = m1y; s_v[g][3][lane] = m1z;

    float f0 = 0.f, f1x = 0.f, f1y = 0.f, f1z = 0.f;
    #pragma unroll
    for (int k = 0; k < 32; ++k) {
        float w0 = s_wl[k*32 + lane], w1 = s_wl[1024 + k*32 + lane];
        f0  += s_v[g][0][k] * w0;
        f1x += s_v[g][1][k] * w1;
        f1y += s_v[g][2][k] * w1;
        f1z += s_v[g][3][k] * w1;
    }

    const float* wp = wprod + (size_t)(species[n]*CH + lane) * 5;
    float p0 = wp[0], p1 = wp[1], p2 = wp[2], p3 = wp[3], p4 = wp[4];
    float o0 = p0*f0 + p1*f0*f0 + p2*(f1x*f1x + f1y*f1y + f1z*f1z);
    float s1 = p3 + p4*f0;
    float o1x = s1*f1x, o1y = s1*f1y, o1z = s1*f1z;

    s_v[g][0][lane] = o0; s_v[g][1][lane] = o1x; s_v[g][2][lane] = o1y; s_v[g][3][lane] = o1z;

    float F0 = 0.f, F1x = 0.f, F1y = 0.f, F1z = 0.f;
    #pragma unroll
    for (int k = 0; k < 32; ++k) {
        float w0 = s_wo[k*32 + lane], w1 = s_wo[1024 + k*32 + lane];
        F0  += s_v[g][0][k] * w0;
        F1x += s_v[g][1][k] * w1;
        F1y += s_v[g][2][k] * w1;
        F1z += s_v[g][3][k] * w1;
    }

    if (dout) {
        ((float4*)dout)[(size_t)n*CH + lane] = make_float4(F0, F1x, F1y, F1z);
    } else {
        f[(size_t)n*CH + lane]          = F0;
        f[NCH + (size_t)n*CH + lane]    = F1x;
        f[2*NCH + (size_t)n*CH + lane]  = F1y;
        f[3*NCH + (size_t)n*CH + lane]  = F1z;
    }
}

extern "C" void kernel_launch(void* const* d_in, const int* in_sizes, int n_in,
                              void* d_out, int out_size, void* d_ws, size_t ws_size,
                              hipStream_t stream)
{
    const float* pos   = (const float*)d_in[0];
    const int* species = (const int*)d_in[1];
    const int* ei      = (const int*)d_in[2];
    const float* wemb  = (const float*)d_in[3];
    const float* wup   = (const float*)d_in[4];
    const float* mw1   = (const float*)d_in[5];
    const float* mw2   = (const float*)d_in[6];
    const float* mw3   = (const float*)d_in[7];
    const float* wlin  = (const float*)d_in[8];
    const float* wprod = (const float*)d_in[9];
    const float* wout  = (const float*)d_in[10];

    char* ws = (char*)d_ws;
    int* cnt   = (int*)ws;
    int* esend = (int*)(ws + 256);
    int* erecv = esend + NEDG;
    float* egeo = (float*)(erecv + NEDG);
    float* f  = egeo + (size_t)NEDG * 12;
    float* fu = f  + 4*(size_t)NCH;
    float* M  = fu + 4*(size_t)NCH;

    hipMemsetAsync(cnt, 0, sizeof(int), stream);
    k_edge_prep<<<(NEDG + 255)/256, 256, 0, stream>>>(pos, ei, cnt, esend, erecv, egeo);
    k_embed<<<(NCH + 255)/256, 256, 0, stream>>>(species, wemb, f);

    for (int i = 0; i < 2; ++i) {
        k_node_linear<<<NN*128/256, 256, 0, stream>>>(f, wup + i*2048, fu);
        hipMemsetAsync(M, 0, 4*(size_t)NCH*sizeof(float), stream);
        k_edge<<<1024, 256, 0, stream>>>(fu, M, mw1 + i*512, mw2 + i*4096, mw3 + i*10240,
                                         esend, erecv, egeo, cnt);
        k_node_out<<<NN/8, 256, 0, stream>>>(M, species, wlin + i*2048, wprod + i*640,
                                             wout + i*2048, f, (i == 1) ? (float*)d_out : nullptr);
    }
}